// Round 9
// baseline (391.822 us; speedup 1.0000x reference)
//
#include <hip/hip_runtime.h>

#define M_NODES 100000
#define NSLAB   6250            // 100000 / 16 exact -> no row predicates
#define GRID    256
#define WAVES   12              // 768 threads; ~155 VGPR -> 3 waves/SIMD
#define NTHR    (WAVES * 64)
#define NSTREAM (GRID * WAVES)  // 3072 independent wave-streams

typedef float  f32x4  __attribute__((ext_vector_type(4)));
typedef short  bf16x8 __attribute__((ext_vector_type(8)));

#define AS1 __attribute__((address_space(1)))
#define AS3 __attribute__((address_space(3)))

static __device__ __forceinline__ unsigned short f2bf(float f) {
  union { float f; unsigned int u; } v; v.f = f;
  return (unsigned short)((v.u + 0x7FFFu + ((v.u >> 16) & 1u)) >> 16);  // RNE
}

static __device__ __forceinline__ bf16x8 cvt8(f32x4 u0, f32x4 u1) {
  union { unsigned int u[4]; bf16x8 v; } r;
  asm("v_cvt_pk_bf16_f32 %0, %1, %2" : "=v"(r.u[0]) : "v"(u0[0]), "v"(u0[1]));
  asm("v_cvt_pk_bf16_f32 %0, %1, %2" : "=v"(r.u[1]) : "v"(u0[2]), "v"(u0[3]));
  asm("v_cvt_pk_bf16_f32 %0, %1, %2" : "=v"(r.u[2]) : "v"(u1[0]), "v"(u1[1]));
  asm("v_cvt_pk_bf16_f32 %0, %1, %2" : "=v"(r.u[3]) : "v"(u1[2]), "v"(u1[3]));
  return r.v;
}

// ---------------------------------------------------------------------------
// prep: W[k][n] f32 -> n-major bf16 image, 512B rows, 16B slots XOR-swizzled:
//   img[n*256 + (((k>>3)^(n&7))<<3) + (k&7)] = bf16(W[k][n])
// (B-frag LDS read at phys slot (kk*4+lhi)^(n&7): correct + conflict-free
//  minimum for ds_read_b128 — validated R7/R8.)
// ---------------------------------------------------------------------------
__global__ void prep_w(const float* __restrict__ W1, const float* __restrict__ W2,
                       unsigned short* __restrict__ U1, unsigned short* __restrict__ U2) {
  int b = blockIdx.x;                        // 512 blocks x 256 threads
  const float* W = (b < 256) ? W1 : W2;
  unsigned short* U = (b < 256) ? U1 : U2;
  int n = b & 255, k = threadIdx.x;
  U[n * 256 + (((k >> 3) ^ (n & 7)) << 3) + (k & 7)] = f2bf(W[k * 256 + n]);
}

// ---------------------------------------------------------------------------
// Wave-autonomous W-stationary streaming pass (R8 structure, spill fixed).
// 256 blocks x 768 thr (12 waves). __launch_bounds__(768,1): allocator free
// -> ~155 VGPR, no scratch, naturally 3 waves/SIMD at 1 block/CU.
// LDS 152KB = W image (128KB, staged once; the ONLY barrier) + 12 x 2KB
// wave-private transpose bufs (pass 1). Zero steady-state sync.
//   A-frags (PASS1): direct global f32 in MFMA-fragment shape.
//   A-frags (PASS2): direct global bf16x8 from frag-major H image (1KB/instr).
//   B-frags: ds_read_b128 from once-staged W image.
//   H write (PASS1): acc -> swizzled 2KB LDS transpose -> 8 x 1KB stores.
// ---------------------------------------------------------------------------
template <int PASS>
__global__ __launch_bounds__(NTHR, 1)
void mlp_pass(const float* __restrict__ Xf,
              const unsigned short* __restrict__ Hin,
              const unsigned short* __restrict__ Wimg,
              const float* __restrict__ bias,
              unsigned short* __restrict__ Hout,
              float* __restrict__ Cout)
{
  __shared__ unsigned short Wl[65536];          // 128 KB
  __shared__ unsigned short Tb[WAVES][1024];    // 12 x 2 KB (pass-1 transpose)

  const int tid  = threadIdx.x;
  const int lane = tid & 63;
  const int l15  = lane & 15;
  const int lhi  = lane >> 4;                   // 0..3
  const int w    = tid >> 6;                    // 0..11
  const int x7   = l15 & 7;

  // ---- one-time: W image -> LDS (linear; image pre-swizzled) -------------
  #pragma unroll
  for (int i = 0; i < 11; ++i) {
    int c = i * WAVES + w;                      // wave-uniform chunk id
    if (c < 128)
      __builtin_amdgcn_global_load_lds(
          (const AS1 unsigned int*)(const void*)(Wimg + c * 512 + lane * 8),
          (AS3 unsigned int*)(void*)(Wl + c * 512), 16, 0, 0);
  }
  float vb[16];
  #pragma unroll
  for (int nf = 0; nf < 16; ++nf) vb[nf] = bias[nf * 16 + l15];
  asm volatile("s_waitcnt vmcnt(0)" ::: "memory");
  __builtin_amdgcn_sched_barrier(0);
  __builtin_amdgcn_s_barrier();                 // the only barrier

  for (int s = blockIdx.x * WAVES + w; s < NSLAB; s += NSTREAM) {
    // ---- A-fragments: direct from global ---------------------------------
    bf16x8 af[8];
    if (PASS == 1) {
      const float* xrow = Xf + (size_t)(s * 16 + l15) * 256;
      #pragma unroll
      for (int kk = 0; kk < 8; ++kk) {
        f32x4 v0 = *(const f32x4*)(xrow + kk * 32 + lhi * 8);
        f32x4 v1 = *(const f32x4*)(xrow + kk * 32 + lhi * 8 + 4);
        af[kk] = cvt8(v0, v1);
      }
    } else {
      const unsigned short* hs = Hin + (size_t)s * 4096;
      #pragma unroll
      for (int kk = 0; kk < 8; ++kk)
        af[kk] = *(const bf16x8*)(hs + kk * 512 + lane * 8);
    }

    // ---- GEMM: 16 rows x 256 cols = 128 MFMA -----------------------------
    f32x4 acc[16];
    #pragma unroll
    for (int nf = 0; nf < 16; ++nf) acc[nf] = f32x4{0.f, 0.f, 0.f, 0.f};
    #pragma unroll
    for (int nf = 0; nf < 16; ++nf) {
      const unsigned short* wr_ = Wl + (nf * 16 + l15) * 256;
      #pragma unroll
      for (int kk = 0; kk < 8; ++kk) {
        bf16x8 bfr = *(const bf16x8*)(wr_ + (((kk * 4 + lhi) ^ x7) << 3));
        acc[nf] = __builtin_amdgcn_mfma_f32_16x16x32_bf16(af[kk], bfr, acc[nf], 0, 0, 0);
      }
    }

    if (PASS == 1) {
      // ---- epilogue 1: bias+relu -> wave-private transpose -> frag-major
      //      H image (8 x 1KB contiguous stores) ---------------------------
      unsigned short* tb = Tb[w];
      unsigned short* hs = Hout + (size_t)s * 4096;
      #pragma unroll
      for (int c = 0; c < 4; ++c) {             // 64-col chunks
        #pragma unroll
        for (int j = 0; j < 4; ++j) {
          int nf = c * 4 + j;
          #pragma unroll
          for (int rg = 0; rg < 4; ++rg) {
            int r = lhi * 4 + rg;
            float v = fmaxf(acc[nf][rg] + vb[nf], 0.f);
            tb[r * 64 + ((((j * 2) + (l15 >> 3)) ^ (r & 7)) << 3) + (l15 & 7)] = f2bf(v);
          }
        }
        asm volatile("s_waitcnt lgkmcnt(0)" ::: "memory");
        __builtin_amdgcn_sched_barrier(0);
        #pragma unroll
        for (int q = 0; q < 2; ++q) {
          int kk = c * 2 + q;
          bf16x8 hv = *(const bf16x8*)(tb + l15 * 64 + (((q * 4 + lhi) ^ x7) << 3));
          *(bf16x8*)(hs + kk * 512 + lane * 8) = hv;   // 1KB coalesced
        }
      }
    } else {
      // ---- epilogue 2: +b2, f32 stores (4-row x 64B segments) ------------
      #pragma unroll
      for (int nf = 0; nf < 16; ++nf) {
        #pragma unroll
        for (int rg = 0; rg < 4; ++rg)
          __builtin_nontemporal_store(acc[nf][rg] + vb[nf],
              Cout + (size_t)(s * 16 + lhi * 4 + rg) * 256 + nf * 16 + l15);
      }
    }
  }
}

// ---------------------------------------------------------------------------
extern "C" void kernel_launch(void* const* d_in, const int* in_sizes, int n_in,
                              void* d_out, int out_size, void* d_ws, size_t ws_size,
                              hipStream_t stream) {
  const float* emb = (const float*)d_in[0];
  const float* W1  = (const float*)d_in[1];
  const float* b1  = (const float*)d_in[2];
  const float* W2  = (const float*)d_in[3];
  const float* b2  = (const float*)d_in[4];
  // d_in[5] = prop_edge_index: unused at ChebConv K=1.
  float* out = (float*)d_out;

  unsigned short* U1   = (unsigned short*)d_ws;  // 65536 ushorts (128 KB)
  unsigned short* U2   = U1 + 65536;             // 128 KB
  unsigned short* Himg = U2 + 65536;             // 6250*4096 ushorts = 51.2 MB

  prep_w<<<512, 256, 0, stream>>>(W1, W2, U1, U2);
  mlp_pass<1><<<GRID, NTHR, 0, stream>>>(emb, nullptr, U1, b1, Himg, nullptr);
  mlp_pass<2><<<GRID, NTHR, 0, stream>>>(nullptr, Himg, U2, b2, nullptr, out);
}

// Round 10
// 355.046 us; speedup vs baseline: 1.1036x; 1.1036x over previous
//
#include <hip/hip_runtime.h>

#define M_NODES 100000
#define NSLAB   6250            // 100000/16 exact -> no row predicates
#define GRID    256
#define WAVES   12              // 768 thr, 12 wave-streams/block, 3/SIMD
#define NTHR    (WAVES * 64)
#define NSTREAM (GRID * WAVES)  // 3072 independent wave-streams

typedef float  f32x4  __attribute__((ext_vector_type(4)));
typedef short  bf16x8 __attribute__((ext_vector_type(8)));

#define AS1 __attribute__((address_space(1)))
#define AS3 __attribute__((address_space(3)))

static __device__ __forceinline__ unsigned short f2bf(float f) {
  union { float f; unsigned int u; } v; v.f = f;
  return (unsigned short)((v.u + 0x7FFFu + ((v.u >> 16) & 1u)) >> 16);  // RNE
}

static __device__ __forceinline__ bf16x8 cvt8(f32x4 u0, f32x4 u1) {
  union { unsigned int u[4]; bf16x8 v; } r;
  asm("v_cvt_pk_bf16_f32 %0, %1, %2" : "=v"(r.u[0]) : "v"(u0[0]), "v"(u0[1]));
  asm("v_cvt_pk_bf16_f32 %0, %1, %2" : "=v"(r.u[1]) : "v"(u0[2]), "v"(u0[3]));
  asm("v_cvt_pk_bf16_f32 %0, %1, %2" : "=v"(r.u[2]) : "v"(u1[0]), "v"(u1[1]));
  asm("v_cvt_pk_bf16_f32 %0, %1, %2" : "=v"(r.u[3]) : "v"(u1[2]), "v"(u1[3]));
  return r.v;
}

// ---------------------------------------------------------------------------
// prep: W[k][n] f32 -> n-major bf16 image, 512B rows, 16B slots XOR-swizzled:
//   img[n*256 + (((k>>3)^(n&7))<<3) + (k&7)] = bf16(W[k][n])
// (B-frag LDS read at phys slot (kk*4+lhi)^(n&7): correctness-validated
//  R7/R8/R9; conflict-free minimum for ds_read_b128.)
// ---------------------------------------------------------------------------
__global__ void prep_w(const float* __restrict__ W1, const float* __restrict__ W2,
                       unsigned short* __restrict__ U1, unsigned short* __restrict__ U2) {
  int b = blockIdx.x;                        // 512 blocks x 256 threads
  const float* W = (b < 256) ? W1 : W2;
  unsigned short* U = (b < 256) ? U1 : U2;
  int n = b & 255, k = threadIdx.x;
  U[n * 256 + (((k >> 3) ^ (n & 7)) << 3) + (k & 7)] = f2bf(W[k * 256 + n]);
}

// ---------------------------------------------------------------------------
// Wave-autonomous W-stationary streaming pass — LOW-PRESSURE edition.
// R8/R9 structure (validated layouts) with the live set halved: each slab's
// 256 output cols are done in TWO halves (acc[8] per half) while af[8] stays
// live across halves (X/H read once). Peak live ~76 VGPR < the 84 the
// backend allocates for 768-thr kernels -> no scratch.
//   A-frags (PASS1): direct global f32 in MFMA-fragment shape (128B lines).
//   A-frags (PASS2): direct global bf16x8 from frag-major H image (1KB/instr).
//   B-frags: ds_read_b128 from once-staged 128KB W LDS image (only barrier).
//   H write (PASS1): acc -> 2KB wave-private LDS transpose -> 1KB stores.
// Zero steady-state sync; TLP = 12 waves/CU.
// ---------------------------------------------------------------------------
template <int PASS>
__global__ __launch_bounds__(NTHR, 1)
void mlp_pass(const float* __restrict__ Xf,
              const unsigned short* __restrict__ Hin,
              const unsigned short* __restrict__ Wimg,
              const float* __restrict__ bias,
              unsigned short* __restrict__ Hout,
              float* __restrict__ Cout)
{
  __shared__ unsigned short Wl[65536];          // 128 KB
  __shared__ unsigned short Tb[WAVES * 1024];   // 12 x 2 KB transpose bufs

  const int tid  = threadIdx.x;
  const int lane = tid & 63;
  const int l15  = lane & 15;
  const int lhi  = lane >> 4;                   // 0..3
  const int w    = tid >> 6;                    // 0..11
  const int x7   = l15 & 7;

  // ---- one-time: W image -> LDS (linear; image pre-swizzled) -------------
  #pragma unroll
  for (int i = 0; i < 11; ++i) {
    int c = i * WAVES + w;                      // wave-uniform chunk id
    if (c < 128)
      __builtin_amdgcn_global_load_lds(
          (const AS1 unsigned int*)(const void*)(Wimg + c * 512 + lane * 8),
          (AS3 unsigned int*)(void*)(Wl + c * 512), 16, 0, 0);
  }
  asm volatile("s_waitcnt vmcnt(0)" ::: "memory");
  __builtin_amdgcn_sched_barrier(0);
  __builtin_amdgcn_s_barrier();                 // the only barrier

  for (int s = blockIdx.x * WAVES + w; s < NSLAB; s += NSTREAM) {
    // ---- A-fragments: direct from global, kept live across both halves --
    bf16x8 af[8];
    if (PASS == 1) {
      const float* xrow = Xf + (size_t)(s * 16 + l15) * 256;
      #pragma unroll
      for (int kk = 0; kk < 8; ++kk) {
        f32x4 v0 = *(const f32x4*)(xrow + kk * 32 + lhi * 8);
        f32x4 v1 = *(const f32x4*)(xrow + kk * 32 + lhi * 8 + 4);
        af[kk] = cvt8(v0, v1);
      }
    } else {
      const unsigned short* hsrc = Hin + (size_t)s * 4096;
      #pragma unroll
      for (int kk = 0; kk < 8; ++kk)
        af[kk] = *(const bf16x8*)(hsrc + kk * 512 + lane * 8);
    }

    // ---- two column-halves: acc[8] live per half -------------------------
    #pragma unroll
    for (int h = 0; h < 2; ++h) {
      f32x4 acc[8];
      #pragma unroll
      for (int nf = 0; nf < 8; ++nf) acc[nf] = f32x4{0.f, 0.f, 0.f, 0.f};
      #pragma unroll
      for (int nf = 0; nf < 8; ++nf) {
        const unsigned short* wr_ = Wl + (size_t)(h * 128 + nf * 16 + l15) * 256;
        #pragma unroll
        for (int kk = 0; kk < 8; ++kk) {
          bf16x8 bfr = *(const bf16x8*)(wr_ + (((kk * 4 + lhi) ^ x7) << 3));
          acc[nf] = __builtin_amdgcn_mfma_f32_16x16x32_bf16(af[kk], bfr, acc[nf], 0, 0, 0);
        }
      }

      if (PASS == 1) {
        // epilogue: bias+relu -> 2KB LDS transpose -> frag-major H (1KB/st)
        unsigned short* tb = Tb + w * 1024;
        unsigned short* hs = Hout + (size_t)s * 4096;
        #pragma unroll
        for (int c2 = 0; c2 < 2; ++c2) {        // 64-col chunks in this half
          #pragma unroll
          for (int j = 0; j < 4; ++j) {
            int nf = c2 * 4 + j;
            float bn = bias[h * 128 + nf * 16 + l15];
            #pragma unroll
            for (int rg = 0; rg < 4; ++rg) {
              int r = lhi * 4 + rg;
              float v = fmaxf(acc[nf][rg] + bn, 0.f);
              tb[r * 64 + (((j * 2 + (l15 >> 3)) ^ (r & 7)) << 3) + (l15 & 7)] = f2bf(v);
            }
          }
          asm volatile("s_waitcnt lgkmcnt(0)" ::: "memory");
          __builtin_amdgcn_sched_barrier(0);
          #pragma unroll
          for (int q = 0; q < 2; ++q) {
            int kk = h * 4 + c2 * 2 + q;
            bf16x8 hv = *(const bf16x8*)(tb + l15 * 64 + (((q * 4 + lhi) ^ x7) << 3));
            *(bf16x8*)(hs + kk * 512 + lane * 8) = hv;   // 1KB coalesced
          }
          asm volatile("s_waitcnt lgkmcnt(0)" ::: "memory");
          __builtin_amdgcn_sched_barrier(0);
        }
      } else {
        // epilogue: +b2, f32 stores (64B segments x 4 rows)
        #pragma unroll
        for (int nf = 0; nf < 8; ++nf) {
          float bn = bias[h * 128 + nf * 16 + l15];
          #pragma unroll
          for (int rg = 0; rg < 4; ++rg)
            __builtin_nontemporal_store(acc[nf][rg] + bn,
                Cout + (size_t)(s * 16 + lhi * 4 + rg) * 256 + h * 128 + nf * 16 + l15);
        }
      }
    }
  }
}

// ---------------------------------------------------------------------------
extern "C" void kernel_launch(void* const* d_in, const int* in_sizes, int n_in,
                              void* d_out, int out_size, void* d_ws, size_t ws_size,
                              hipStream_t stream) {
  const float* emb = (const float*)d_in[0];
  const float* W1  = (const float*)d_in[1];
  const float* b1  = (const float*)d_in[2];
  const float* W2  = (const float*)d_in[3];
  const float* b2  = (const float*)d_in[4];
  // d_in[5] = prop_edge_index: unused at ChebConv K=1.
  float* out = (float*)d_out;

  unsigned short* U1   = (unsigned short*)d_ws;  // 65536 ushorts (128 KB)
  unsigned short* U2   = U1 + 65536;             // 128 KB
  unsigned short* Himg = U2 + 65536;             // 6250*4096 ushorts = 51.2 MB

  prep_w<<<512, 256, 0, stream>>>(W1, W2, U1, U2);
  mlp_pass<1><<<GRID, NTHR, 0, stream>>>(emb, nullptr, U1, b1, Himg, nullptr);
  mlp_pass<2><<<GRID, NTHR, 0, stream>>>(nullptr, Himg, U2, b2, nullptr, out);
}